// Round 9
// baseline (375.898 us; speedup 1.0000x reference)
//
#include <hip/hip_runtime.h>
#include <hip/hip_bf16.h>

// Problem constants
#define BB 2
#define TT 2048
#define DD 512
#define HH 8
#define DH 64
#define INNER 512
#define MAXLAG 5

typedef __attribute__((ext_vector_type(8))) short short8;
typedef __attribute__((ext_vector_type(4))) float floatx4;
typedef unsigned short ushort_t;

__device__ inline unsigned short f2bf(float f) {
    unsigned u = __float_as_uint(f);
    unsigned r = (u + 0x7FFFu + ((u >> 16) & 1u)) >> 16;
    return (unsigned short)r;
}
__device__ inline float bf2f(unsigned short u) {
    return __uint_as_float(((unsigned)u) << 16);
}

// ---------------------------------------------------------------------------
// Fused convert: blocks [0,1024): x -> bf16; blocks [1024,2048): weight
// transpose+convert via 32x32 LDS tile (Wt[n][k] = bf16(W[k][n])).
// ---------------------------------------------------------------------------
__global__ __launch_bounds__(256)
void cvt_kernel(const float* __restrict__ x,
                const float* __restrict__ wq, const float* __restrict__ wk,
                const float* __restrict__ wv, const float* __restrict__ wo,
                ushort_t* __restrict__ xb,
                ushort_t* __restrict__ wqt, ushort_t* __restrict__ wkt,
                ushort_t* __restrict__ wvt, ushort_t* __restrict__ wot)
{
    __shared__ float T[32][33];
    const int bid = blockIdx.x;
    if (bid < 1024) {
        int off = (bid * 256 + threadIdx.x) * 8;
        float4 a = *(const float4*)&x[off];
        float4 b = *(const float4*)&x[off + 4];
        ushort_t t[8];
        t[0] = f2bf(a.x); t[1] = f2bf(a.y); t[2] = f2bf(a.z); t[3] = f2bf(a.w);
        t[4] = f2bf(b.x); t[5] = f2bf(b.y); t[6] = f2bf(b.z); t[7] = f2bf(b.w);
        *(uint4*)&xb[off] = *(const uint4*)t;
        return;
    }
    const int r = bid - 1024;
    const int z = r >> 8;
    const int tile = r & 255;
    const float* s = (z == 0) ? wq : (z == 1) ? wk : (z == 2) ? wv : wo;
    ushort_t*    d = (z == 0) ? wqt : (z == 1) ? wkt : (z == 2) ? wvt : wot;
    const int k0 = (tile & 15) * 32;
    const int n0 = (tile >> 4) * 32;
    {
        const int kk = threadIdx.x >> 3;
        const int n4 = (threadIdx.x & 7) * 4;
        float4 v = *(const float4*)&s[(size_t)(k0 + kk) * 512 + n0 + n4];
        T[kk][n4 + 0] = v.x; T[kk][n4 + 1] = v.y;
        T[kk][n4 + 2] = v.z; T[kk][n4 + 3] = v.w;
    }
    __syncthreads();
    {
        const int nn = threadIdx.x >> 3;
        const int k4 = (threadIdx.x & 7) * 4;
        ushort4 o;
        o.x = f2bf(T[k4 + 0][nn]); o.y = f2bf(T[k4 + 1][nn]);
        o.z = f2bf(T[k4 + 2][nn]); o.w = f2bf(T[k4 + 3][nn]);
        *(ushort4*)&d[(size_t)(n0 + nn) * 512 + k0 + k4] = o;
    }
}

// ---------------------------------------------------------------------------
// bf16 MFMA GEMM, 64x64 tiles, GK=64 (two MFMA k-steps per barrier round --
// half the barriers of R7). Fragment-granule LDS: granule g = m*8 + c
// (c = dim/8), 16B each; all reads/writes at the b128 bank floor.
// vtrans: blockIdx.z==2 writes V TRANSPOSED: O2[((b*8+h)*64+d)*2048 + t].
// ---------------------------------------------------------------------------
#define GM 64
#define GN 64
#define GK 64

template <typename OutT>
__global__ __launch_bounds__(256)
void gemm64(const ushort_t* __restrict__ A,
            const ushort_t* __restrict__ B0, const ushort_t* __restrict__ B1,
            const ushort_t* __restrict__ B2,
            OutT* __restrict__ O0, OutT* __restrict__ O1, OutT* __restrict__ O2,
            const float* __restrict__ bias, int M, int N, int K, int vtrans)
{
    const ushort_t* Bw = (blockIdx.z == 0) ? B0 : ((blockIdx.z == 1) ? B1 : B2);
    OutT*           O  = (blockIdx.z == 0) ? O0 : ((blockIdx.z == 1) ? O1 : O2);
    const int dotrans = vtrans && (blockIdx.z == 2);

    __shared__ ushort_t As[GM * GK];   // 512 granules: g = m*8 + c
    __shared__ ushort_t Bs[GN * GK];

    const int tid  = threadIdx.x;
    const int wave = tid >> 6;
    const int lane = tid & 63;
    const int quad = lane >> 4;
    const int l15  = lane & 15;
    const int wr   = wave >> 1;
    const int wc   = wave & 1;
    const int bm   = blockIdx.y * GM;
    const int bn   = blockIdx.x * GN;

    // staging: thread t owns granules t and t+256:
    //   g=t:     m = t>>3,      c = t&7
    //   g=t+256: m = 32+(t>>3), c = t&7
    const int sm = tid >> 3;
    const int sc = (tid & 7) * 8;
    const ushort_t* ap0 = &A[(size_t)(bm + sm) * K + sc];
    const ushort_t* ap1 = &A[(size_t)(bm + 32 + sm) * K + sc];
    const ushort_t* bp0 = &Bw[(size_t)(bn + sm) * K + sc];
    const ushort_t* bp1 = &Bw[(size_t)(bn + 32 + sm) * K + sc];

    floatx4 acc[2][2];
#pragma unroll
    for (int i = 0; i < 2; ++i)
#pragma unroll
        for (int j = 0; j < 2; ++j) acc[i][j] = (floatx4){0.f, 0.f, 0.f, 0.f};

    uint4 pa0 = *(const uint4*)ap0, pa1 = *(const uint4*)ap1;
    uint4 pb0 = *(const uint4*)bp0, pb1 = *(const uint4*)bp1;

    for (int k0 = 0; k0 < K; k0 += GK) {
        __syncthreads();
        *(uint4*)&As[tid * 8]            = pa0;
        *(uint4*)&As[(tid + 256) * 8]    = pa1;
        *(uint4*)&Bs[tid * 8]            = pb0;
        *(uint4*)&Bs[(tid + 256) * 8]    = pb1;
        if (k0 + GK < K) {
            pa0 = *(const uint4*)(ap0 + k0 + GK);
            pa1 = *(const uint4*)(ap1 + k0 + GK);
            pb0 = *(const uint4*)(bp0 + k0 + GK);
            pb1 = *(const uint4*)(bp1 + k0 + GK);
        }
        __syncthreads();

#pragma unroll
        for (int ks = 0; ks < 2; ++ks) {
            short8 af[2], bf[2];
#pragma unroll
            for (int mt = 0; mt < 2; ++mt)
                af[mt] = *(const short8*)&As[(((wr * 32 + mt * 16 + l15) << 3) + ks * 4 + quad) * 8];
#pragma unroll
            for (int nt = 0; nt < 2; ++nt)
                bf[nt] = *(const short8*)&Bs[(((wc * 32 + nt * 16 + l15) << 3) + ks * 4 + quad) * 8];
#pragma unroll
            for (int mt = 0; mt < 2; ++mt)
#pragma unroll
                for (int nt = 0; nt < 2; ++nt)
                    acc[mt][nt] = __builtin_amdgcn_mfma_f32_16x16x32_bf16(
                        af[mt], bf[nt], acc[mt][nt], 0, 0, 0);
        }
    }

    if (dotrans) {
#pragma unroll
        for (int mt = 0; mt < 2; ++mt) {
            const int m0 = bm + wr * 32 + mt * 16 + quad * 4;
            const int b  = m0 >> 11;
            const int t0 = m0 & 2047;
#pragma unroll
            for (int nt = 0; nt < 2; ++nt) {
                const int n = bn + wc * 32 + nt * 16 + l15;
                const int h = n >> 6, dd = n & 63;
                ushort4 o;
                o.x = f2bf(acc[mt][nt][0]); o.y = f2bf(acc[mt][nt][1]);
                o.z = f2bf(acc[mt][nt][2]); o.w = f2bf(acc[mt][nt][3]);
                *(ushort4*)&((ushort_t*)O)[((size_t)((b * 8 + h) * 64 + dd)) * 2048 + t0] = o;
            }
        }
        return;
    }

    float bv[2] = {0.f, 0.f};
    if (bias) {
#pragma unroll
        for (int nt = 0; nt < 2; ++nt)
            bv[nt] = bias[bn + wc * 32 + nt * 16 + l15];
    }
#pragma unroll
    for (int mt = 0; mt < 2; ++mt) {
#pragma unroll
        for (int nt = 0; nt < 2; ++nt) {
            const int n = bn + wc * 32 + nt * 16 + l15;
#pragma unroll
            for (int reg = 0; reg < 4; ++reg) {
                const int m = bm + wr * 32 + mt * 16 + quad * 4 + reg;
                float v = acc[mt][nt][reg] + bv[nt];
                if constexpr (sizeof(OutT) == 2)
                    O[(size_t)m * N + n] = (OutT)f2bf(v);
                else
                    O[(size_t)m * N + n] = (OutT)v;
            }
        }
    }
}

// ---------------------------------------------------------------------------
// MFMA flash attention v5: BARRIER-FREE, wave-private. Block = 1 wave (64
// threads). grid (64, 4, 16): chunk c -> qt=31-(c>>1), sp=c&1 (2-way K-split,
// heavy first); blockIdx.y = q-slice (16 rows); blockIdx.z = bh.
// Each wave stages its own 32-key sub-tiles (K: 32x64, V^T: 64x32) into
// private LDS (9.5 KB/block -> ~16 blocks/CU), swizzled granules, register
// prefetch one sub-tile ahead. Same-wave DS ordering => NO __syncthreads.
// Fixed-max softmax (MFIX). Fully-masked sub-tiles skipped via sub_hi clip.
// ---------------------------------------------------------------------------
#define PPAD 40
#define MFIX 10.0f

__global__ __launch_bounds__(64, 4)
void attn_mfma(const ushort_t* __restrict__ Qg,
               const ushort_t* __restrict__ Kg,
               const ushort_t* __restrict__ Vtg,
               const float* __restrict__ lagw,
               ushort_t* __restrict__ Opart,
               float* __restrict__ Lpart)
{
    __shared__ ushort_t Ksub[32 * 64];      // granule g = krow*8 + ((kch+krow)&7)
    __shared__ ushort_t Vsub[64 * 32];      // granule g = vrow*4 + ((vch+vrow)&3)
    __shared__ ushort_t Pl[16][PPAD];

    const int lane = threadIdx.x;
    const int quad = lane >> 4;
    const int l15  = lane & 15;

    const int bh = blockIdx.z;
    const int b  = bh >> 3;
    const int h  = bh & 7;
    const int c  = blockIdx.x;          // heavy qt first
    const int qt = 31 - (c >> 1);
    const int sp = c & 1;
    const int h1 = (qt + 1) >> 1;
    const int lo = sp ? h1 : 0;
    const int hi = sp ? (qt + 1) : h1;
    const int i0q = qt * 64 + blockIdx.y * 16;   // this wave's 16 q-rows

    // sub-tile (32-key) range; clip fully-masked tiles (keys > i0q+15)
    const int s_lo = 2 * lo;
    const int s_hi = min(2 * hi, ((i0q + 15) >> 5) + 1);

    float lagb[MAXLAG + 1];
    {
        float mx = -1e30f;
#pragma unroll
        for (int l = 0; l <= MAXLAG; ++l) {
            lagb[l] = lagw[h * (MAXLAG + 1) + l];
            mx = fmaxf(mx, lagb[l]);
        }
        float s = 0.f;
#pragma unroll
        for (int l = 0; l <= MAXLAG; ++l) { lagb[l] = __expf(lagb[l] - mx); s += lagb[l]; }
        float inv = 1.f / s;
#pragma unroll
        for (int l = 0; l <= MAXLAG; ++l) lagb[l] = lagb[l] * inv - MFIX;
    }
    const float c1  = 0.125f;
    const float c2f = lagb[MAXLAG];

    short8 qf0, qf1;
    {
        const ushort_t* qbase =
            Qg + ((size_t)(b * TT + i0q + l15)) * INNER + h * DH;
        qf0 = *(const short8*)(qbase + quad * 8);
        qf1 = *(const short8*)(qbase + 32 + quad * 8);
    }

    floatx4 oacc[4];
    float lsum[4] = {0.f, 0.f, 0.f, 0.f};
#pragma unroll
    for (int db = 0; db < 4; ++db) oacc[db] = (floatx4){0.f, 0.f, 0.f, 0.f};

    const int ibase = i0q + quad * 4;

    // staging bases: lane covers K granules (r0+8i, kch) and V (v0+16i, vch)
    const int r0  = lane >> 3, kch = lane & 7;
    const int v0  = lane >> 2, vch = lane & 3;
    const ushort_t* Kp = Kg + ((size_t)(b * TT) + r0) * INNER + h * DH + kch * 8;
    const ushort_t* Vp = Vtg + ((size_t)(bh * 64 + v0)) * 2048 + vch * 8;
    const int kdst0 = ((r0 << 3) + ((kch + r0) & 7)) << 3;
    const int vdst0 = ((v0 << 2) + ((vch + v0) & 3)) << 3;

    uint4 pk[4], pv[4];
    if (s_lo < s_hi) {
        const int j0 = s_lo * 32;
#pragma unroll
        for (int i = 0; i < 4; ++i) {
            pk[i] = *(const uint4*)(Kp + (size_t)(j0 + 8 * i) * INNER);
            pv[i] = *(const uint4*)(Vp + (size_t)(16 * i) * 2048 + j0);
        }
    }

    for (int s = s_lo; s < s_hi; ++s) {
        const int j0 = s * 32;

        // commit staged sub-tiles (wave-private; same-wave DS order, no barrier)
#pragma unroll
        for (int i = 0; i < 4; ++i) {
            *(uint4*)&Ksub[kdst0 + i * 512] = pk[i];
            *(uint4*)&Vsub[vdst0 + i * 512] = pv[i];
        }
        // prefetch next sub-tile
        if (s + 1 < s_hi) {
            const int jn = j0 + 32;
#pragma unroll
            for (int i = 0; i < 4; ++i) {
                pk[i] = *(const uint4*)(Kp + (size_t)(jn + 8 * i) * INNER);
                pv[i] = *(const uint4*)(Vp + (size_t)(16 * i) * 2048 + jn);
            }
        }

        // S = Q @ K^T  (16 q-rows x 32 keys, 2 col-blocks)
        floatx4 sacc[2];
#pragma unroll
        for (int cb = 0; cb < 2; ++cb) {
            const int key = cb * 16 + l15;
            short8 kf0 = *(const short8*)&Ksub[((key << 3) + ((quad + key) & 7)) << 3];
            short8 kf1 = *(const short8*)&Ksub[((key << 3) + ((quad + 4 + key) & 7)) << 3];
            floatx4 z = (floatx4){0.f, 0.f, 0.f, 0.f};
            z = __builtin_amdgcn_mfma_f32_16x16x32_bf16(qf0, kf0, z, 0, 0, 0);
            z = __builtin_amdgcn_mfma_f32_16x16x32_bf16(qf1, kf1, z, 0, 0, 0);
            sacc[cb] = z;
        }

        // fixed-max softmax weights
        float p[2][4];
        if (i0q - (j0 + 31) >= MAXLAG) {
#pragma unroll
            for (int cb = 0; cb < 2; ++cb)
#pragma unroll
                for (int reg = 0; reg < 4; ++reg)
                    p[cb][reg] = __expf(fmaf(sacc[cb][reg], c1, c2f));
        } else {
#pragma unroll
            for (int cb = 0; cb < 2; ++cb) {
                const int j = j0 + cb * 16 + l15;
#pragma unroll
                for (int reg = 0; reg < 4; ++reg) {
                    const int lag = (ibase + reg) - j;
                    float bias = (lag <= 0) ? lagb[0]
                               : (lag == 1) ? lagb[1]
                               : (lag == 2) ? lagb[2]
                               : (lag == 3) ? lagb[3]
                               : (lag == 4) ? lagb[4] : lagb[5];
                    float e = __expf(fmaf(sacc[cb][reg], c1, bias));
                    p[cb][reg] = (lag < 0) ? 0.f : e;
                }
            }
        }
#pragma unroll
        for (int cb = 0; cb < 2; ++cb)
#pragma unroll
            for (int reg = 0; reg < 4; ++reg)
                lsum[reg] += p[cb][reg];

        // P: C-layout -> LDS -> A-layout (wave-private)
#pragma unroll
        for (int cb = 0; cb < 2; ++cb)
#pragma unroll
            for (int reg = 0; reg < 4; ++reg)
                Pl[quad * 4 + reg][cb * 16 + l15] = f2bf(p[cb][reg]);

        short8 pf = *(const short8*)&Pl[l15][quad * 8];

        // O += P @ V  (K-dim = 32 -> one MFMA per d-block)
#pragma unroll
        for (int db = 0; db < 4; ++db) {
            const int d = db * 16 + l15;
            short8 vf = *(const short8*)&Vsub[((d << 2) + ((quad + d) & 3)) << 3];
            oacc[db] = __builtin_amdgcn_mfma_f32_16x16x32_bf16(pf, vf, oacc[db], 0, 0, 0);
        }
    }

#pragma unroll
    for (int reg = 0; reg < 4; ++reg) {
        lsum[reg] += __shfl_xor(lsum[reg], 1);
        lsum[reg] += __shfl_xor(lsum[reg], 2);
        lsum[reg] += __shfl_xor(lsum[reg], 4);
        lsum[reg] += __shfl_xor(lsum[reg], 8);
    }

#pragma unroll
    for (int reg = 0; reg < 4; ++reg) {
        const int row = ibase + reg;
        const size_t obase = ((size_t)(sp * 16 + bh) * TT + row) * 64;
#pragma unroll
        for (int db = 0; db < 4; ++db)
            Opart[obase + db * 16 + l15] = f2bf(oacc[db][reg]);
        if (l15 == 0)
            Lpart[(size_t)(sp * 16 + bh) * TT + row] = lsum[reg];
    }
}

// ---------------------------------------------------------------------------
// Combine the 2 K-split partials -> ao bf16 [b*T+i][h*64+d]
// ---------------------------------------------------------------------------
#define CMB_UNITS (16 * TT * 16)

__global__ __launch_bounds__(256)
void combine_kernel(const ushort_t* __restrict__ Opart,
                    const float* __restrict__ Lpart,
                    ushort_t* __restrict__ ao)
{
    int u = blockIdx.x * 256 + threadIdx.x;
    const int bh  = u >> 15;
    const int rem = u & 32767;
    const int i   = rem >> 4;
    const int d   = (rem & 15) * 4;
    const int b   = bh >> 3;
    const int h   = bh & 7;

    const size_t p0 = ((size_t)bh * TT + i) * 64 + d;
    const size_t p1 = ((size_t)(16 + bh) * TT + i) * 64 + d;
    ushort4 a0 = *(const ushort4*)&Opart[p0];
    ushort4 a1 = *(const ushort4*)&Opart[p1];
    const float l = Lpart[(size_t)bh * TT + i] + Lpart[(size_t)(16 + bh) * TT + i];
    const float inv = 1.f / l;

    ushort4 o;
    o.x = f2bf((bf2f(a0.x) + bf2f(a1.x)) * inv);
    o.y = f2bf((bf2f(a0.y) + bf2f(a1.y)) * inv);
    o.z = f2bf((bf2f(a0.z) + bf2f(a1.z)) * inv);
    o.w = f2bf((bf2f(a0.w) + bf2f(a1.w)) * inv);
    *(ushort4*)&ao[((size_t)(b * TT + i)) * INNER + h * DH + d] = o;
}

// ---------------------------------------------------------------------------
extern "C" void kernel_launch(void* const* d_in, const int* in_sizes, int n_in,
                              void* d_out, int out_size, void* d_ws, size_t ws_size,
                              hipStream_t stream)
{
    const float* x  = (const float*)d_in[0];
    const float* Wq = (const float*)d_in[1];
    const float* Wk = (const float*)d_in[2];
    const float* Wv = (const float*)d_in[3];
    const float* Wo = (const float*)d_in[4];
    const float* bo = (const float*)d_in[5];
    const float* lw = (const float*)d_in[6];
    float* out = (float*)d_out;

    const size_t SZ  = (size_t)BB * TT * INNER;  // 2M elements
    const size_t NWE = (size_t)DD * INNER;       // 256K per weight
    ushort_t* xb    = (ushort_t*)d_ws;
    ushort_t* wqt   = xb + SZ;
    ushort_t* wkt   = wqt + NWE;
    ushort_t* wvt   = wkt + NWE;
    ushort_t* wot   = wvt + NWE;
    ushort_t* q     = wot + NWE;
    ushort_t* k     = q + SZ;
    ushort_t* vt    = k + SZ;                    // V TRANSPOSED [bh][d][t]
    ushort_t* opart = vt + SZ;                   // 2 slots * 16*TT*64
    float*    lpart = (float*)(opart + 2 * SZ);
    ushort_t* ao    = xb;                        // alias: xb dead after QKV

    const int M = BB * TT;

    cvt_kernel<<<2048, 256, 0, stream>>>(x, Wq, Wk, Wv, Wo,
                                         xb, wqt, wkt, wvt, wot);

    dim3 gQKV(INNER / GN, M / GM, 3);
    gemm64<ushort_t><<<gQKV, 256, 0, stream>>>(
        xb, wqt, wkt, wvt, q, k, vt, nullptr, M, INNER, DD, 1);

    dim3 gATT(64, 4, BB * HH);
    attn_mfma<<<gATT, 64, 0, stream>>>(q, k, vt, lw, opart, lpart);

    combine_kernel<<<CMB_UNITS / 256, 256, 0, stream>>>(opart, lpart, ao);

    dim3 gPRJ(DD / GN, M / GM, 1);
    gemm64<float><<<gPRJ, 256, 0, stream>>>(
        ao, wot, wot, wot, out, out, out, bo, M, DD, INNER, 0);
}

// Round 10
// 174.066 us; speedup vs baseline: 2.1595x; 2.1595x over previous
//
#include <hip/hip_runtime.h>
#include <hip/hip_bf16.h>

// Problem constants
#define BB 2
#define TT 2048
#define DD 512
#define HH 8
#define DH 64
#define INNER 512
#define MAXLAG 5

typedef __attribute__((ext_vector_type(8))) short short8;
typedef __attribute__((ext_vector_type(4))) float floatx4;
typedef unsigned short ushort_t;

__device__ inline unsigned short f2bf(float f) {
    unsigned u = __float_as_uint(f);
    unsigned r = (u + 0x7FFFu + ((u >> 16) & 1u)) >> 16;
    return (unsigned short)r;
}
__device__ inline float bf2f(unsigned short u) {
    return __uint_as_float(((unsigned)u) << 16);
}

// ---------------------------------------------------------------------------
// Fused convert (R7 verbatim): blocks [0,1024): x -> bf16; [1024,2048):
// weight transpose+convert via 32x32 LDS tile (Wt[n][k] = bf16(W[k][n])).
// ---------------------------------------------------------------------------
__global__ __launch_bounds__(256)
void cvt_kernel(const float* __restrict__ x,
                const float* __restrict__ wq, const float* __restrict__ wk,
                const float* __restrict__ wv, const float* __restrict__ wo,
                ushort_t* __restrict__ xb,
                ushort_t* __restrict__ wqt, ushort_t* __restrict__ wkt,
                ushort_t* __restrict__ wvt, ushort_t* __restrict__ wot)
{
    __shared__ float T[32][33];
    const int bid = blockIdx.x;
    if (bid < 1024) {
        int off = (bid * 256 + threadIdx.x) * 8;
        float4 a = *(const float4*)&x[off];
        float4 b = *(const float4*)&x[off + 4];
        ushort_t t[8];
        t[0] = f2bf(a.x); t[1] = f2bf(a.y); t[2] = f2bf(a.z); t[3] = f2bf(a.w);
        t[4] = f2bf(b.x); t[5] = f2bf(b.y); t[6] = f2bf(b.z); t[7] = f2bf(b.w);
        *(uint4*)&xb[off] = *(const uint4*)t;
        return;
    }
    const int r = bid - 1024;
    const int z = r >> 8;
    const int tile = r & 255;
    const float* s = (z == 0) ? wq : (z == 1) ? wk : (z == 2) ? wv : wo;
    ushort_t*    d = (z == 0) ? wqt : (z == 1) ? wkt : (z == 2) ? wvt : wot;
    const int k0 = (tile & 15) * 32;
    const int n0 = (tile >> 4) * 32;
    {
        const int kk = threadIdx.x >> 3;
        const int n4 = (threadIdx.x & 7) * 4;
        float4 v = *(const float4*)&s[(size_t)(k0 + kk) * 512 + n0 + n4];
        T[kk][n4 + 0] = v.x; T[kk][n4 + 1] = v.y;
        T[kk][n4 + 2] = v.z; T[kk][n4 + 3] = v.w;
    }
    __syncthreads();
    {
        const int nn = threadIdx.x >> 3;
        const int k4 = (threadIdx.x & 7) * 4;
        ushort4 o;
        o.x = f2bf(T[k4 + 0][nn]); o.y = f2bf(T[k4 + 1][nn]);
        o.z = f2bf(T[k4 + 2][nn]); o.w = f2bf(T[k4 + 3][nn]);
        *(ushort4*)&d[(size_t)(n0 + nn) * 512 + k0 + k4] = o;
    }
}

// ---------------------------------------------------------------------------
// QKV GEMM: 128x128x64 bf16 MFMA. 4 waves (2x2), each 64x64 via 4x4 MFMAs.
// Fragment-granule LDS (granule g = row*8 + kchunk, 16B); staging thread t
// owns granules t+256i (rows (t>>3)+32i, chunk t&7) -> 128B/row coalesced.
// Register prefetch. blockIdx.z picks Wq/Wk/Wv; z==2 writes V TRANSPOSED:
// O2[((b*8+h)*64+d)*2048 + t] (validated in R7/R9).
// ---------------------------------------------------------------------------
#define QBM 128
#define QBN 128
#define QBK 64

__global__ __launch_bounds__(256)
void qkv128(const ushort_t* __restrict__ A,
            const ushort_t* __restrict__ B0, const ushort_t* __restrict__ B1,
            const ushort_t* __restrict__ B2,
            ushort_t* __restrict__ O0, ushort_t* __restrict__ O1,
            ushort_t* __restrict__ O2)
{
    const ushort_t* Bw = (blockIdx.z == 0) ? B0 : ((blockIdx.z == 1) ? B1 : B2);
    ushort_t*       O  = (blockIdx.z == 0) ? O0 : ((blockIdx.z == 1) ? O1 : O2);
    const int dotrans = (blockIdx.z == 2);
    const int K = DD;   // 512

    __shared__ ushort_t As[QBM * QBK];   // 1024 granules
    __shared__ ushort_t Bs[QBN * QBK];

    const int tid  = threadIdx.x;
    const int wave = tid >> 6;
    const int lane = tid & 63;
    const int quad = lane >> 4;
    const int l15  = lane & 15;
    const int wr   = wave >> 1;
    const int wc   = wave & 1;
    const int bm   = blockIdx.y * QBM;
    const int bn   = blockIdx.x * QBN;

    const int sr  = tid >> 3;        // 0..31
    const int sc8 = (tid & 7) * 8;
    const ushort_t* ap[4];
    const ushort_t* bp[4];
#pragma unroll
    for (int i = 0; i < 4; ++i) {
        ap[i] = &A[(size_t)(bm + sr + 32 * i) * K + sc8];
        bp[i] = &Bw[(size_t)(bn + sr + 32 * i) * K + sc8];
    }

    floatx4 acc[4][4];
#pragma unroll
    for (int i = 0; i < 4; ++i)
#pragma unroll
        for (int j = 0; j < 4; ++j) acc[i][j] = (floatx4){0.f, 0.f, 0.f, 0.f};

    uint4 pa[4], pb[4];
#pragma unroll
    for (int i = 0; i < 4; ++i) { pa[i] = *(const uint4*)ap[i]; pb[i] = *(const uint4*)bp[i]; }

    for (int k0 = 0; k0 < K; k0 += QBK) {
        __syncthreads();
#pragma unroll
        for (int i = 0; i < 4; ++i) {
            *(uint4*)&As[(tid + 256 * i) * 8] = pa[i];
            *(uint4*)&Bs[(tid + 256 * i) * 8] = pb[i];
        }
        if (k0 + QBK < K) {
#pragma unroll
            for (int i = 0; i < 4; ++i) {
                pa[i] = *(const uint4*)(ap[i] + k0 + QBK);
                pb[i] = *(const uint4*)(bp[i] + k0 + QBK);
            }
        }
        __syncthreads();

#pragma unroll
        for (int ks = 0; ks < 2; ++ks) {
            short8 af[4], bf[4];
#pragma unroll
            for (int mt = 0; mt < 4; ++mt)
                af[mt] = *(const short8*)&As[(((wr * 64 + mt * 16 + l15) << 3) + ks * 4 + quad) * 8];
#pragma unroll
            for (int nt = 0; nt < 4; ++nt)
                bf[nt] = *(const short8*)&Bs[(((wc * 64 + nt * 16 + l15) << 3) + ks * 4 + quad) * 8];
#pragma unroll
            for (int mt = 0; mt < 4; ++mt)
#pragma unroll
                for (int nt = 0; nt < 4; ++nt)
                    acc[mt][nt] = __builtin_amdgcn_mfma_f32_16x16x32_bf16(
                        af[mt], bf[nt], acc[mt][nt], 0, 0, 0);
        }
    }

    if (dotrans) {
#pragma unroll
        for (int mt = 0; mt < 4; ++mt) {
            const int m0 = bm + wr * 64 + mt * 16 + quad * 4;
            const int b  = m0 >> 11;
            const int t0 = m0 & 2047;
#pragma unroll
            for (int nt = 0; nt < 4; ++nt) {
                const int n = bn + wc * 64 + nt * 16 + l15;
                const int h = n >> 6, dd = n & 63;
                ushort4 o;
                o.x = f2bf(acc[mt][nt][0]); o.y = f2bf(acc[mt][nt][1]);
                o.z = f2bf(acc[mt][nt][2]); o.w = f2bf(acc[mt][nt][3]);
                *(ushort4*)&O[((size_t)((b * 8 + h) * 64 + dd)) * 2048 + t0] = o;
            }
        }
        return;
    }

#pragma unroll
    for (int mt = 0; mt < 4; ++mt) {
#pragma unroll
        for (int nt = 0; nt < 4; ++nt) {
            const int n = bn + wc * 64 + nt * 16 + l15;
#pragma unroll
            for (int reg = 0; reg < 4; ++reg) {
                const int m = bm + wr * 64 + mt * 16 + quad * 4 + reg;
                O[(size_t)m * INNER + n] = f2bf(acc[mt][nt][reg]);
            }
        }
    }
}

// ---------------------------------------------------------------------------
// MFMA flash attention (R7 VERBATIM -- best measured config).
// ---------------------------------------------------------------------------
#define PAD 72
#define MFIX 10.0f

__global__ __launch_bounds__(256)
void attn_mfma(const ushort_t* __restrict__ Qg,
               const ushort_t* __restrict__ Kg,
               const ushort_t* __restrict__ Vtg,
               const float* __restrict__ lagw,
               ushort_t* __restrict__ Opart,
               float* __restrict__ Lpart)
{
    __shared__ ushort_t Ks[64 * 8 * 8];
    __shared__ ushort_t Vts[64 * 8 * 8];
    __shared__ ushort_t Pl[4][16][PAD];

    const int tid  = threadIdx.x;
    const int wave = tid >> 6;
    const int lane = tid & 63;
    const int quad = lane >> 4;
    const int l15  = lane & 15;

    const int bh = blockIdx.y;
    const int b  = bh >> 3;
    const int h  = bh & 7;
    const int c  = blockIdx.x;
    const int qt = 31 - (c >> 1);
    const int sp = c & 1;
    const int i0 = qt * 64;
    const int h1 = (qt + 1) >> 1;
    const int lo = sp ? h1 : 0;
    const int hi = sp ? (qt + 1) : h1;

    float lagb[MAXLAG + 1];
    {
        float mx = -1e30f;
#pragma unroll
        for (int l = 0; l <= MAXLAG; ++l) {
            lagb[l] = lagw[h * (MAXLAG + 1) + l];
            mx = fmaxf(mx, lagb[l]);
        }
        float s = 0.f;
#pragma unroll
        for (int l = 0; l <= MAXLAG; ++l) { lagb[l] = __expf(lagb[l] - mx); s += lagb[l]; }
        float inv = 1.f / s;
#pragma unroll
        for (int l = 0; l <= MAXLAG; ++l) lagb[l] = lagb[l] * inv - MFIX;
    }
    const float c1  = 0.125f;
    const float c2f = lagb[MAXLAG];

    short8 qf0, qf1;
    {
        const ushort_t* qbase =
            Qg + ((size_t)(b * TT + i0 + wave * 16 + l15)) * INNER + h * DH;
        qf0 = *(const short8*)(qbase + quad * 8);
        qf1 = *(const short8*)(qbase + 32 + quad * 8);
    }

    floatx4 oacc[4];
    float lsum[4] = {0.f, 0.f, 0.f, 0.f};
#pragma unroll
    for (int cb = 0; cb < 4; ++cb) oacc[cb] = (floatx4){0.f, 0.f, 0.f, 0.f};

    const int ibase = i0 + wave * 16 + quad * 4;

    const int srow = tid >> 3;
    const int sc   = tid & 7;
    const ushort_t* Kp0 = Kg + ((size_t)(b * TT) + srow) * INNER + h * DH + sc * 8;
    const ushort_t* Kp1 = Kp0 + (size_t)32 * INNER;
    const ushort_t* Vp0 = Vtg + ((size_t)(bh * 64 + srow)) * 2048 + sc * 8;
    const ushort_t* Vp1 = Vp0 + (size_t)32 * 2048;
    const int slot = (sc + srow) & 7;
    const int kdst0 = ((srow << 3) + slot) << 3;
    const int kdst1 = (((srow + 32) << 3) + slot) << 3;

    uint4 pk0, pk1, pv0, pv1;
    if (lo < hi) {
        const size_t koff = (size_t)(lo * 64) * INNER;
        pk0 = *(const uint4*)(Kp0 + koff);
        pk1 = *(const uint4*)(Kp1 + koff);
        pv0 = *(const uint4*)(Vp0 + lo * 64);
        pv1 = *(const uint4*)(Vp1 + lo * 64);
    }

    for (int kt = lo; kt < hi; ++kt) {
        __syncthreads();
        *(uint4*)&Ks[kdst0]  = pk0;
        *(uint4*)&Ks[kdst1]  = pk1;
        *(uint4*)&Vts[kdst0] = pv0;
        *(uint4*)&Vts[kdst1] = pv1;
        if (kt + 1 < hi) {
            const size_t koff = (size_t)((kt + 1) * 64) * INNER;
            pk0 = *(const uint4*)(Kp0 + koff);
            pk1 = *(const uint4*)(Kp1 + koff);
            pv0 = *(const uint4*)(Vp0 + (kt + 1) * 64);
            pv1 = *(const uint4*)(Vp1 + (kt + 1) * 64);
        }
        __syncthreads();

        const int j0 = kt * 64;

        floatx4 sacc[4];
#pragma unroll
        for (int cb = 0; cb < 4; ++cb) {
            const int key = cb * 16 + l15;
            short8 kf0 = *(const short8*)&Ks[((key << 3) + ((quad + key) & 7)) << 3];
            short8 kf1 = *(const short8*)&Ks[((key << 3) + ((quad + 4 + key) & 7)) << 3];
            floatx4 z = (floatx4){0.f, 0.f, 0.f, 0.f};
            z = __builtin_amdgcn_mfma_f32_16x16x32_bf16(qf0, kf0, z, 0, 0, 0);
            z = __builtin_amdgcn_mfma_f32_16x16x32_bf16(qf1, kf1, z, 0, 0, 0);
            sacc[cb] = z;
        }

        float p[4][4];
        if (i0 + wave * 16 - (j0 + 63) >= MAXLAG) {
#pragma unroll
            for (int cb = 0; cb < 4; ++cb)
#pragma unroll
                for (int reg = 0; reg < 4; ++reg)
                    p[cb][reg] = __expf(fmaf(sacc[cb][reg], c1, c2f));
        } else {
#pragma unroll
            for (int cb = 0; cb < 4; ++cb) {
                const int j = j0 + cb * 16 + l15;
#pragma unroll
                for (int reg = 0; reg < 4; ++reg) {
                    const int lag = (ibase + reg) - j;
                    float bias = (lag <= 0) ? lagb[0]
                               : (lag == 1) ? lagb[1]
                               : (lag == 2) ? lagb[2]
                               : (lag == 3) ? lagb[3]
                               : (lag == 4) ? lagb[4] : lagb[5];
                    float e = __expf(fmaf(sacc[cb][reg], c1, bias));
                    p[cb][reg] = (lag < 0) ? 0.f : e;
                }
            }
        }
#pragma unroll
        for (int cb = 0; cb < 4; ++cb)
#pragma unroll
            for (int reg = 0; reg < 4; ++reg)
                lsum[reg] += p[cb][reg];

#pragma unroll
        for (int cb = 0; cb < 4; ++cb)
#pragma unroll
            for (int reg = 0; reg < 4; ++reg)
                Pl[wave][quad * 4 + reg][cb * 16 + l15] = f2bf(p[cb][reg]);

        short8 pf0 = *(const short8*)&Pl[wave][l15][quad * 8];
        short8 pf1 = *(const short8*)&Pl[wave][l15][32 + quad * 8];

#pragma unroll
        for (int cb = 0; cb < 4; ++cb) {
            const int dd = cb * 16 + l15;
            short8 vf0 = *(const short8*)&Vts[((dd << 3) + ((quad + dd) & 7)) << 3];
            short8 vf1 = *(const short8*)&Vts[((dd << 3) + ((quad + 4 + dd) & 7)) << 3];
            oacc[cb] = __builtin_amdgcn_mfma_f32_16x16x32_bf16(pf0, vf0, oacc[cb], 0, 0, 0);
            oacc[cb] = __builtin_amdgcn_mfma_f32_16x16x32_bf16(pf1, vf1, oacc[cb], 0, 0, 0);
        }
    }

#pragma unroll
    for (int reg = 0; reg < 4; ++reg) {
        lsum[reg] += __shfl_xor(lsum[reg], 1);
        lsum[reg] += __shfl_xor(lsum[reg], 2);
        lsum[reg] += __shfl_xor(lsum[reg], 4);
        lsum[reg] += __shfl_xor(lsum[reg], 8);
    }

#pragma unroll
    for (int reg = 0; reg < 4; ++reg) {
        const int row = ibase + reg;
        const size_t obase = ((size_t)(sp * 16 + bh) * TT + row) * 64;
#pragma unroll
        for (int cb = 0; cb < 4; ++cb)
            Opart[obase + cb * 16 + l15] = f2bf(oacc[cb][reg]);
        if (l15 == 0)
            Lpart[(size_t)(sp * 16 + bh) * TT + row] = lsum[reg];
    }
}

// ---------------------------------------------------------------------------
// Projection GEMM with FUSED COMBINE: A[m][k] = (opart0 + opart1) * Linv,
// built in staging from opart[slot][bh][t][d] (k = h*64+d; h uniform per
// k-iter since QBK=64). Linv[h][r] precomputed in LDS per block. 128x128x64,
// fp32 output + bias.
// ---------------------------------------------------------------------------
__global__ __launch_bounds__(256)
void proj128(const ushort_t* __restrict__ Opart,
             const float* __restrict__ Lpart,
             const ushort_t* __restrict__ Bw,   // wot[n][k]
             const float* __restrict__ bias,
             float* __restrict__ O)
{
    const int K = INNER;  // 512

    __shared__ ushort_t As[QBM * QBK];
    __shared__ ushort_t Bs[QBN * QBK];
    __shared__ float Linv[8 * 128];     // [h][r]

    const int tid  = threadIdx.x;
    const int wave = tid >> 6;
    const int lane = tid & 63;
    const int quad = lane >> 4;
    const int l15  = lane & 15;
    const int wr   = wave >> 1;
    const int wc   = wave & 1;
    const int bm   = blockIdx.y * QBM;
    const int bn   = blockIdx.x * QBN;

    const int bblk  = bm >> 11;        // batch (uniform per block)
    const int tbase = bm & 2047;

    // precompute Linv[h][r] = 1/(l_slot0 + l_slot1)
#pragma unroll
    for (int i = 0; i < 4; ++i) {
        const int idx = tid + 256 * i;       // h = idx>>7, r = idx&127
        const int h = idx >> 7, r = idx & 127;
        const size_t p = (size_t)(bblk * 8 + h) * 2048 + tbase + r;
        Linv[idx] = 1.f / (Lpart[p] + Lpart[(size_t)16 * 2048 + p]);
    }

    const int sr  = tid >> 3;        // 0..31
    const int sc8 = (tid & 7) * 8;   // d-offset 0..56
    // opart element offsets for rows sr+32i (slot 0); slot 1 adds 16*2048*64
    size_t aoff[4];
#pragma unroll
    for (int i = 0; i < 4; ++i)
        aoff[i] = ((size_t)(bblk * 8) * 2048 + (tbase + sr + 32 * i)) * 64 + sc8;
    const size_t SLOT = (size_t)16 * 2048 * 64;
    const size_t HSTEP = (size_t)2048 * 64;    // h -> h+1

    const ushort_t* bp[4];
#pragma unroll
    for (int i = 0; i < 4; ++i)
        bp[i] = &Bw[(size_t)(bn + sr + 32 * i) * K + sc8];

    floatx4 acc[4][4];
#pragma unroll
    for (int i = 0; i < 4; ++i)
#pragma unroll
        for (int j = 0; j < 4; ++j) acc[i][j] = (floatx4){0.f, 0.f, 0.f, 0.f};

    uint4 pa0[4], pa1[4], pb[4];
#pragma unroll
    for (int i = 0; i < 4; ++i) {
        pa0[i] = *(const uint4*)&Opart[aoff[i]];
        pa1[i] = *(const uint4*)&Opart[aoff[i] + SLOT];
        pb[i]  = *(const uint4*)bp[i];
    }

    for (int k0 = 0; k0 < K; k0 += QBK) {
        const int h = k0 >> 6;
        __syncthreads();
#pragma unroll
        for (int i = 0; i < 4; ++i) {
            const float inv = Linv[h * 128 + sr + 32 * i];
            const ushort_t* a0 = (const ushort_t*)&pa0[i];
            const ushort_t* a1 = (const ushort_t*)&pa1[i];
            ushort_t t[8];
#pragma unroll
            for (int j = 0; j < 8; ++j)
                t[j] = f2bf((bf2f(a0[j]) + bf2f(a1[j])) * inv);
            *(uint4*)&As[(tid + 256 * i) * 8] = *(const uint4*)t;
            *(uint4*)&Bs[(tid + 256 * i) * 8] = pb[i];
        }
        if (k0 + QBK < K) {
#pragma unroll
            for (int i = 0; i < 4; ++i) {
                pa0[i] = *(const uint4*)&Opart[aoff[i] + HSTEP * (h + 1)];
                pa1[i] = *(const uint4*)&Opart[aoff[i] + HSTEP * (h + 1) + SLOT];
                pb[i]  = *(const uint4*)(bp[i] + k0 + QBK);
            }
        }
        __syncthreads();

#pragma unroll
        for (int ks = 0; ks < 2; ++ks) {
            short8 af[4], bf[4];
#pragma unroll
            for (int mt = 0; mt < 4; ++mt)
                af[mt] = *(const short8*)&As[(((wr * 64 + mt * 16 + l15) << 3) + ks * 4 + quad) * 8];
#pragma unroll
            for (int nt = 0; nt < 4; ++nt)
                bf[nt] = *(const short8*)&Bs[(((wc * 64 + nt * 16 + l15) << 3) + ks * 4 + quad) * 8];
#pragma unroll
            for (int mt = 0; mt < 4; ++mt)
#pragma unroll
                for (int nt = 0; nt < 4; ++nt)
                    acc[mt][nt] = __builtin_amdgcn_mfma_f32_16x16x32_bf16(
                        af[mt], bf[nt], acc[mt][nt], 0, 0, 0);
        }
    }

    float bv[4];
#pragma unroll
    for (int nt = 0; nt < 4; ++nt)
        bv[nt] = bias[bn + wc * 64 + nt * 16 + l15];
#pragma unroll
    for (int mt = 0; mt < 4; ++mt) {
#pragma unroll
        for (int nt = 0; nt < 4; ++nt) {
            const int n = bn + wc * 64 + nt * 16 + l15;
#pragma unroll
            for (int reg = 0; reg < 4; ++reg) {
                const int m = bm + wr * 64 + mt * 16 + quad * 4 + reg;
                O[(size_t)m * DD + n] = acc[mt][nt][reg] + bv[nt];
            }
        }
    }
}

// ---------------------------------------------------------------------------
extern "C" void kernel_launch(void* const* d_in, const int* in_sizes, int n_in,
                              void* d_out, int out_size, void* d_ws, size_t ws_size,
                              hipStream_t stream)
{
    const float* x  = (const float*)d_in[0];
    const float* Wq = (const float*)d_in[1];
    const float* Wk = (const float*)d_in[2];
    const float* Wv = (const float*)d_in[3];
    const float* Wo = (const float*)d_in[4];
    const float* bo = (const float*)d_in[5];
    const float* lw = (const float*)d_in[6];
    float* out = (float*)d_out;

    const size_t SZ  = (size_t)BB * TT * INNER;  // 2M elements
    const size_t NWE = (size_t)DD * INNER;       // 256K per weight
    ushort_t* xb    = (ushort_t*)d_ws;
    ushort_t* wqt   = xb + SZ;
    ushort_t* wkt   = wqt + NWE;
    ushort_t* wvt   = wkt + NWE;
    ushort_t* wot   = wvt + NWE;
    ushort_t* q     = wot + NWE;
    ushort_t* k     = q + SZ;
    ushort_t* vt    = k + SZ;                    // V TRANSPOSED [bh][d][t]
    ushort_t* opart = vt + SZ;                   // 2 slots * 16*TT*64
    float*    lpart = (float*)(opart + 2 * SZ);

    const int M = BB * TT;

    cvt_kernel<<<2048, 256, 0, stream>>>(x, Wq, Wk, Wv, Wo,
                                         xb, wqt, wkt, wvt, wot);

    dim3 gQKV(INNER / QBN, M / QBM, 3);
    qkv128<<<gQKV, 256, 0, stream>>>(xb, wqt, wkt, wvt, q, k, vt);

    dim3 gATT(64, BB * HH);
    attn_mfma<<<gATT, 256, 0, stream>>>(q, k, vt, lw, opart, lpart);

    dim3 gPRJ(DD / QBN, M / QBM);
    proj128<<<gPRJ, 256, 0, stream>>>(opart, lpart, wot, bo, out);
}

// Round 11
// 139.074 us; speedup vs baseline: 2.7029x; 1.2516x over previous
//
#include <hip/hip_runtime.h>
#include <hip/hip_bf16.h>

// Problem constants
#define BB 2
#define TT 2048
#define DD 512
#define HH 8
#define DH 64
#define INNER 512
#define MAXLAG 5

typedef __attribute__((ext_vector_type(8))) short short8;
typedef __attribute__((ext_vector_type(4))) float floatx4;
typedef unsigned short ushort_t;

__device__ inline unsigned short f2bf(float f) {
    unsigned u = __float_as_uint(f);
    unsigned r = (u + 0x7FFFu + ((u >> 16) & 1u)) >> 16;
    return (unsigned short)r;
}
__device__ inline float bf2f(unsigned short u) {
    return __uint_as_float(((unsigned)u) << 16);
}

// ---------------------------------------------------------------------------
// Fused convert (R7 verbatim): blocks [0,1024): x -> bf16; [1024,2048):
// weight transpose+convert via 32x32 LDS tile (Wt[n][k] = bf16(W[k][n])).
// ---------------------------------------------------------------------------
__global__ __launch_bounds__(256)
void cvt_kernel(const float* __restrict__ x,
                const float* __restrict__ wq, const float* __restrict__ wk,
                const float* __restrict__ wv, const float* __restrict__ wo,
                ushort_t* __restrict__ xb,
                ushort_t* __restrict__ wqt, ushort_t* __restrict__ wkt,
                ushort_t* __restrict__ wvt, ushort_t* __restrict__ wot)
{
    __shared__ float T[32][33];
    const int bid = blockIdx.x;
    if (bid < 1024) {
        int off = (bid * 256 + threadIdx.x) * 8;
        float4 a = *(const float4*)&x[off];
        float4 b = *(const float4*)&x[off + 4];
        ushort_t t[8];
        t[0] = f2bf(a.x); t[1] = f2bf(a.y); t[2] = f2bf(a.z); t[3] = f2bf(a.w);
        t[4] = f2bf(b.x); t[5] = f2bf(b.y); t[6] = f2bf(b.z); t[7] = f2bf(b.w);
        *(uint4*)&xb[off] = *(const uint4*)t;
        return;
    }
    const int r = bid - 1024;
    const int z = r >> 8;
    const int tile = r & 255;
    const float* s = (z == 0) ? wq : (z == 1) ? wk : (z == 2) ? wv : wo;
    ushort_t*    d = (z == 0) ? wqt : (z == 1) ? wkt : (z == 2) ? wvt : wot;
    const int k0 = (tile & 15) * 32;
    const int n0 = (tile >> 4) * 32;
    {
        const int kk = threadIdx.x >> 3;
        const int n4 = (threadIdx.x & 7) * 4;
        float4 v = *(const float4*)&s[(size_t)(k0 + kk) * 512 + n0 + n4];
        T[kk][n4 + 0] = v.x; T[kk][n4 + 1] = v.y;
        T[kk][n4 + 2] = v.z; T[kk][n4 + 3] = v.w;
    }
    __syncthreads();
    {
        const int nn = threadIdx.x >> 3;
        const int k4 = (threadIdx.x & 7) * 4;
        ushort4 o;
        o.x = f2bf(T[k4 + 0][nn]); o.y = f2bf(T[k4 + 1][nn]);
        o.z = f2bf(T[k4 + 2][nn]); o.w = f2bf(T[k4 + 3][nn]);
        *(ushort4*)&d[(size_t)(n0 + nn) * 512 + k0 + k4] = o;
    }
}

// ---------------------------------------------------------------------------
// QKV GEMM (R7 gemm64 core, GK=32, 1536 blocks = 6/CU). blockIdx.z==2
// writes V TRANSPOSED in 64-key TILES: vt[((bh*32+kt)*64+d)*64 + tl] --
// each (d, tile) row is one 128B line fully covered by this block, killing
// the R10-measured 3x write amplification of the 2048-strided layout.
// ---------------------------------------------------------------------------
#define GM 64
#define GN 64
#define GK 32

__global__ __launch_bounds__(256)
void qkv64(const ushort_t* __restrict__ A,
           const ushort_t* __restrict__ B0, const ushort_t* __restrict__ B1,
           const ushort_t* __restrict__ B2,
           ushort_t* __restrict__ O0, ushort_t* __restrict__ O1,
           ushort_t* __restrict__ O2)
{
    const ushort_t* Bw = (blockIdx.z == 0) ? B0 : ((blockIdx.z == 1) ? B1 : B2);
    ushort_t*       O  = (blockIdx.z == 0) ? O0 : ((blockIdx.z == 1) ? O1 : O2);
    const int dotrans = (blockIdx.z == 2);
    const int K = DD;

    __shared__ ushort_t As[GM * GK];   // granule g = m*4+c -> A[m][c*8..+8]
    __shared__ ushort_t Bs[GN * GK];

    const int tid  = threadIdx.x;
    const int wave = tid >> 6;
    const int lane = tid & 63;
    const int quad = lane >> 4;
    const int l15  = lane & 15;
    const int wr   = wave >> 1;
    const int wc   = wave & 1;
    const int bm   = blockIdx.y * GM;
    const int bn   = blockIdx.x * GN;

    const ushort_t* ap = &A[(size_t)(bm + (tid >> 2)) * K + (tid & 3) * 8];
    const ushort_t* bp = &Bw[(size_t)(bn + (tid >> 2)) * K + (tid & 3) * 8];

    floatx4 acc[2][2];
#pragma unroll
    for (int i = 0; i < 2; ++i)
#pragma unroll
        for (int j = 0; j < 2; ++j) acc[i][j] = (floatx4){0.f, 0.f, 0.f, 0.f};

    uint4 pa = *(const uint4*)ap;
    uint4 pb = *(const uint4*)bp;

    for (int k0 = 0; k0 < K; k0 += GK) {
        __syncthreads();
        *(uint4*)&As[tid * 8] = pa;
        *(uint4*)&Bs[tid * 8] = pb;
        if (k0 + GK < K) {
            pa = *(const uint4*)(ap + k0 + GK);
            pb = *(const uint4*)(bp + k0 + GK);
        }
        __syncthreads();

        short8 af[2], bf[2];
#pragma unroll
        for (int mt = 0; mt < 2; ++mt)
            af[mt] = *(const short8*)&As[(((wr * 32 + mt * 16 + l15) << 2) + quad) * 8];
#pragma unroll
        for (int nt = 0; nt < 2; ++nt)
            bf[nt] = *(const short8*)&Bs[(((wc * 32 + nt * 16 + l15) << 2) + quad) * 8];
#pragma unroll
        for (int mt = 0; mt < 2; ++mt)
#pragma unroll
            for (int nt = 0; nt < 2; ++nt)
                acc[mt][nt] = __builtin_amdgcn_mfma_f32_16x16x32_bf16(
                    af[mt], bf[nt], acc[mt][nt], 0, 0, 0);
    }

    if (dotrans) {
        // V^T tiled store: vt[((b*8+h)*32 + kt)*64 + dd][tl..tl+3]
#pragma unroll
        for (int mt = 0; mt < 2; ++mt) {
            const int m0 = bm + wr * 32 + mt * 16 + quad * 4;
            const int b  = m0 >> 11;
            const int t0 = m0 & 2047;
            const int kt = t0 >> 6;
            const int tl = t0 & 63;
#pragma unroll
            for (int nt = 0; nt < 2; ++nt) {
                const int n = bn + wc * 32 + nt * 16 + l15;
                const int h = n >> 6, dd = n & 63;
                ushort4 o;
                o.x = f2bf(acc[mt][nt][0]); o.y = f2bf(acc[mt][nt][1]);
                o.z = f2bf(acc[mt][nt][2]); o.w = f2bf(acc[mt][nt][3]);
                *(ushort4*)&O[(((size_t)((b * 8 + h) * 32 + kt)) * 64 + dd) * 64 + tl] = o;
            }
        }
        return;
    }

#pragma unroll
    for (int mt = 0; mt < 2; ++mt) {
#pragma unroll
        for (int nt = 0; nt < 2; ++nt) {
            const int n = bn + wc * 32 + nt * 16 + l15;
#pragma unroll
            for (int reg = 0; reg < 4; ++reg) {
                const int m = bm + wr * 32 + mt * 16 + quad * 4 + reg;
                O[(size_t)m * INNER + n] = f2bf(acc[mt][nt][reg]);
            }
        }
    }
}

// ---------------------------------------------------------------------------
// MFMA flash attention (R7 verbatim core; only the GLOBAL V^T source
// addresses change to the tiled layout -- LDS side identical).
// ---------------------------------------------------------------------------
#define PAD 72
#define MFIX 10.0f

__global__ __launch_bounds__(256)
void attn_mfma(const ushort_t* __restrict__ Qg,
               const ushort_t* __restrict__ Kg,
               const ushort_t* __restrict__ Vtg,
               const float* __restrict__ lagw,
               ushort_t* __restrict__ Opart,
               float* __restrict__ Lpart)
{
    __shared__ ushort_t Ks[64 * 8 * 8];
    __shared__ ushort_t Vts[64 * 8 * 8];
    __shared__ ushort_t Pl[4][16][PAD];

    const int tid  = threadIdx.x;
    const int wave = tid >> 6;
    const int lane = tid & 63;
    const int quad = lane >> 4;
    const int l15  = lane & 15;

    const int bh = blockIdx.y;
    const int b  = bh >> 3;
    const int h  = bh & 7;
    const int c  = blockIdx.x;
    const int qt = 31 - (c >> 1);
    const int sp = c & 1;
    const int i0 = qt * 64;
    const int h1 = (qt + 1) >> 1;
    const int lo = sp ? h1 : 0;
    const int hi = sp ? (qt + 1) : h1;

    float lagb[MAXLAG + 1];
    {
        float mx = -1e30f;
#pragma unroll
        for (int l = 0; l <= MAXLAG; ++l) {
            lagb[l] = lagw[h * (MAXLAG + 1) + l];
            mx = fmaxf(mx, lagb[l]);
        }
        float s = 0.f;
#pragma unroll
        for (int l = 0; l <= MAXLAG; ++l) { lagb[l] = __expf(lagb[l] - mx); s += lagb[l]; }
        float inv = 1.f / s;
#pragma unroll
        for (int l = 0; l <= MAXLAG; ++l) lagb[l] = lagb[l] * inv - MFIX;
    }
    const float c1  = 0.125f;
    const float c2f = lagb[MAXLAG];

    short8 qf0, qf1;
    {
        const ushort_t* qbase =
            Qg + ((size_t)(b * TT + i0 + wave * 16 + l15)) * INNER + h * DH;
        qf0 = *(const short8*)(qbase + quad * 8);
        qf1 = *(const short8*)(qbase + 32 + quad * 8);
    }

    floatx4 oacc[4];
    float lsum[4] = {0.f, 0.f, 0.f, 0.f};
#pragma unroll
    for (int cb = 0; cb < 4; ++cb) oacc[cb] = (floatx4){0.f, 0.f, 0.f, 0.f};

    const int ibase = i0 + wave * 16 + quad * 4;

    const int srow = tid >> 3;
    const int sc   = tid & 7;
    const ushort_t* Kp0 = Kg + ((size_t)(b * TT) + srow) * INNER + h * DH + sc * 8;
    const ushort_t* Kp1 = Kp0 + (size_t)32 * INNER;
    // tiled V^T: base for (bh, kt=0, d=srow): per kt add 4096; d+32 adds 2048
    const ushort_t* Vp0 = Vtg + ((size_t)bh * 32 * 64 + srow) * 64 + sc * 8;
    const ushort_t* Vp1 = Vp0 + 32 * 64;
    const int slot = (sc + srow) & 7;
    const int kdst0 = ((srow << 3) + slot) << 3;
    const int kdst1 = (((srow + 32) << 3) + slot) << 3;

    uint4 pk0, pk1, pv0, pv1;
    if (lo < hi) {
        const size_t koff = (size_t)(lo * 64) * INNER;
        pk0 = *(const uint4*)(Kp0 + koff);
        pk1 = *(const uint4*)(Kp1 + koff);
        pv0 = *(const uint4*)(Vp0 + lo * 4096);
        pv1 = *(const uint4*)(Vp1 + lo * 4096);
    }

    for (int kt = lo; kt < hi; ++kt) {
        __syncthreads();
        *(uint4*)&Ks[kdst0]  = pk0;
        *(uint4*)&Ks[kdst1]  = pk1;
        *(uint4*)&Vts[kdst0] = pv0;
        *(uint4*)&Vts[kdst1] = pv1;
        if (kt + 1 < hi) {
            const size_t koff = (size_t)((kt + 1) * 64) * INNER;
            pk0 = *(const uint4*)(Kp0 + koff);
            pk1 = *(const uint4*)(Kp1 + koff);
            pv0 = *(const uint4*)(Vp0 + (kt + 1) * 4096);
            pv1 = *(const uint4*)(Vp1 + (kt + 1) * 4096);
        }
        __syncthreads();

        const int j0 = kt * 64;

        floatx4 sacc[4];
#pragma unroll
        for (int cb = 0; cb < 4; ++cb) {
            const int key = cb * 16 + l15;
            short8 kf0 = *(const short8*)&Ks[((key << 3) + ((quad + key) & 7)) << 3];
            short8 kf1 = *(const short8*)&Ks[((key << 3) + ((quad + 4 + key) & 7)) << 3];
            floatx4 z = (floatx4){0.f, 0.f, 0.f, 0.f};
            z = __builtin_amdgcn_mfma_f32_16x16x32_bf16(qf0, kf0, z, 0, 0, 0);
            z = __builtin_amdgcn_mfma_f32_16x16x32_bf16(qf1, kf1, z, 0, 0, 0);
            sacc[cb] = z;
        }

        float p[4][4];
        if (i0 + wave * 16 - (j0 + 63) >= MAXLAG) {
#pragma unroll
            for (int cb = 0; cb < 4; ++cb)
#pragma unroll
                for (int reg = 0; reg < 4; ++reg)
                    p[cb][reg] = __expf(fmaf(sacc[cb][reg], c1, c2f));
        } else {
#pragma unroll
            for (int cb = 0; cb < 4; ++cb) {
                const int j = j0 + cb * 16 + l15;
#pragma unroll
                for (int reg = 0; reg < 4; ++reg) {
                    const int lag = (ibase + reg) - j;
                    float bias = (lag <= 0) ? lagb[0]
                               : (lag == 1) ? lagb[1]
                               : (lag == 2) ? lagb[2]
                               : (lag == 3) ? lagb[3]
                               : (lag == 4) ? lagb[4] : lagb[5];
                    float e = __expf(fmaf(sacc[cb][reg], c1, bias));
                    p[cb][reg] = (lag < 0) ? 0.f : e;
                }
            }
        }
#pragma unroll
        for (int cb = 0; cb < 4; ++cb)
#pragma unroll
            for (int reg = 0; reg < 4; ++reg)
                lsum[reg] += p[cb][reg];

#pragma unroll
        for (int cb = 0; cb < 4; ++cb)
#pragma unroll
            for (int reg = 0; reg < 4; ++reg)
                Pl[wave][quad * 4 + reg][cb * 16 + l15] = f2bf(p[cb][reg]);

        short8 pf0 = *(const short8*)&Pl[wave][l15][quad * 8];
        short8 pf1 = *(const short8*)&Pl[wave][l15][32 + quad * 8];

#pragma unroll
        for (int cb = 0; cb < 4; ++cb) {
            const int dd = cb * 16 + l15;
            short8 vf0 = *(const short8*)&Vts[((dd << 3) + ((quad + dd) & 7)) << 3];
            short8 vf1 = *(const short8*)&Vts[((dd << 3) + ((quad + 4 + dd) & 7)) << 3];
            oacc[cb] = __builtin_amdgcn_mfma_f32_16x16x32_bf16(pf0, vf0, oacc[cb], 0, 0, 0);
            oacc[cb] = __builtin_amdgcn_mfma_f32_16x16x32_bf16(pf1, vf1, oacc[cb], 0, 0, 0);
        }
    }

#pragma unroll
    for (int reg = 0; reg < 4; ++reg) {
        lsum[reg] += __shfl_xor(lsum[reg], 1);
        lsum[reg] += __shfl_xor(lsum[reg], 2);
        lsum[reg] += __shfl_xor(lsum[reg], 4);
        lsum[reg] += __shfl_xor(lsum[reg], 8);
    }

#pragma unroll
    for (int reg = 0; reg < 4; ++reg) {
        const int row = ibase + reg;
        const size_t obase = ((size_t)(sp * 16 + bh) * TT + row) * 64;
#pragma unroll
        for (int cb = 0; cb < 4; ++cb)
            Opart[obase + cb * 16 + l15] = f2bf(oacc[cb][reg]);
        if (l15 == 0)
            Lpart[(size_t)(sp * 16 + bh) * TT + row] = lsum[reg];
    }
}

// ---------------------------------------------------------------------------
// Projection GEMM (64x64x32, 512 blocks) with FUSED COMBINE: A-tile staged
// as bf16((opart0 + opart1) * Linv[h][row]) -- bitwise-identical values to
// the old combine kernel's output. Linv precomputed in LDS (h uniform per
// k-iter since GK=32 never crosses a 64-wide head).
// ---------------------------------------------------------------------------
__global__ __launch_bounds__(256)
void proj64(const ushort_t* __restrict__ Opart,
            const float* __restrict__ Lpart,
            const ushort_t* __restrict__ Bw,   // wot[n][k]
            const float* __restrict__ bias,
            float* __restrict__ O)
{
    const int K = INNER;

    __shared__ ushort_t As[GM * GK];
    __shared__ ushort_t Bs[GN * GK];
    __shared__ float Linv[8 * 64];      // [h][row]

    const int tid  = threadIdx.x;
    const int wave = tid >> 6;
    const int lane = tid & 63;
    const int quad = lane >> 4;
    const int l15  = lane & 15;
    const int wr   = wave >> 1;
    const int wc   = wave & 1;
    const int bm   = blockIdx.y * GM;
    const int bn   = blockIdx.x * GN;

    const int bblk  = bm >> 11;
    const int tbase = bm & 2047;

    // Linv[h][r] = 1 / (L_slot0 + L_slot1)
    {
        const int i1 = tid;            // h = i1>>6, r = i1&63
        const size_t p1 = (size_t)(bblk * 8 + (i1 >> 6)) * 2048 + tbase + (i1 & 63);
        Linv[i1] = 1.f / (Lpart[p1] + Lpart[(size_t)16 * 2048 + p1]);
        const int i2 = tid + 256;
        const size_t p2 = (size_t)(bblk * 8 + (i2 >> 6)) * 2048 + tbase + (i2 & 63);
        Linv[i2] = 1.f / (Lpart[p2] + Lpart[(size_t)16 * 2048 + p2]);
    }

    const int sr  = tid >> 2;          // 0..63 (row)
    const int sc8 = (tid & 3) * 8;     // 0,8,16,24
    // opart: [slot][b*8+h][t][d]; base for h=0, d=sc8
    const size_t abase = ((size_t)(bblk * 8) * 2048 + tbase + sr) * 64 + sc8;
    const size_t HSTEP = (size_t)2048 * 64;
    const size_t SLOT  = (size_t)16 * 2048 * 64;

    const ushort_t* bp = &Bw[(size_t)(bn + sr) * K + sc8];

    floatx4 acc[2][2];
#pragma unroll
    for (int i = 0; i < 2; ++i)
#pragma unroll
        for (int j = 0; j < 2; ++j) acc[i][j] = (floatx4){0.f, 0.f, 0.f, 0.f};

    uint4 pa0 = *(const uint4*)&Opart[abase];
    uint4 pa1 = *(const uint4*)&Opart[abase + SLOT];
    uint4 pb  = *(const uint4*)bp;

    for (int k0 = 0; k0 < K; k0 += GK) {
        const int h = k0 >> 6;
        __syncthreads();
        {
            const float inv = Linv[h * 64 + sr];
            const ushort_t* a0 = (const ushort_t*)&pa0;
            const ushort_t* a1 = (const ushort_t*)&pa1;
            ushort_t t[8];
#pragma unroll
            for (int j = 0; j < 8; ++j)
                t[j] = f2bf((bf2f(a0[j]) + bf2f(a1[j])) * inv);
            *(uint4*)&As[tid * 8] = *(const uint4*)t;
            *(uint4*)&Bs[tid * 8] = pb;
        }
        if (k0 + GK < K) {
            const int kn = k0 + GK;
            const size_t aoff = abase + HSTEP * (kn >> 6) + (kn & 32);
            pa0 = *(const uint4*)&Opart[aoff];
            pa1 = *(const uint4*)&Opart[aoff + SLOT];
            pb  = *(const uint4*)(bp + kn);
        }
        __syncthreads();

        short8 af[2], bf[2];
#pragma unroll
        for (int mt = 0; mt < 2; ++mt)
            af[mt] = *(const short8*)&As[(((wr * 32 + mt * 16 + l15) << 2) + quad) * 8];
#pragma unroll
        for (int nt = 0; nt < 2; ++nt)
            bf[nt] = *(const short8*)&Bs[(((wc * 32 + nt * 16 + l15) << 2) + quad) * 8];
#pragma unroll
        for (int mt = 0; mt < 2; ++mt)
#pragma unroll
            for (int nt = 0; nt < 2; ++nt)
                acc[mt][nt] = __builtin_amdgcn_mfma_f32_16x16x32_bf16(
                    af[mt], bf[nt], acc[mt][nt], 0, 0, 0);
    }

    float bv[2];
#pragma unroll
    for (int nt = 0; nt < 2; ++nt)
        bv[nt] = bias[bn + wc * 32 + nt * 16 + l15];
#pragma unroll
    for (int mt = 0; mt < 2; ++mt) {
#pragma unroll
        for (int nt = 0; nt < 2; ++nt) {
            const int n = bn + wc * 32 + nt * 16 + l15;
#pragma unroll
            for (int reg = 0; reg < 4; ++reg) {
                const int m = bm + wr * 32 + mt * 16 + quad * 4 + reg;
                O[(size_t)m * DD + n] = acc[mt][nt][reg] + bv[nt];
            }
        }
    }
}

// ---------------------------------------------------------------------------
extern "C" void kernel_launch(void* const* d_in, const int* in_sizes, int n_in,
                              void* d_out, int out_size, void* d_ws, size_t ws_size,
                              hipStream_t stream)
{
    const float* x  = (const float*)d_in[0];
    const float* Wq = (const float*)d_in[1];
    const float* Wk = (const float*)d_in[2];
    const float* Wv = (const float*)d_in[3];
    const float* Wo = (const float*)d_in[4];
    const float* bo = (const float*)d_in[5];
    const float* lw = (const float*)d_in[6];
    float* out = (float*)d_out;

    const size_t SZ  = (size_t)BB * TT * INNER;  // 2M elements
    const size_t NWE = (size_t)DD * INNER;
    ushort_t* xb    = (ushort_t*)d_ws;
    ushort_t* wqt   = xb + SZ;
    ushort_t* wkt   = wqt + NWE;
    ushort_t* wvt   = wkt + NWE;
    ushort_t* wot   = wvt + NWE;
    ushort_t* q     = wot + NWE;
    ushort_t* k     = q + SZ;
    ushort_t* vt    = k + SZ;                    // V^T tiled [bh][kt][d][64]
    ushort_t* opart = vt + SZ;
    float*    lpart = (float*)(opart + 2 * SZ);

    const int M = BB * TT;

    cvt_kernel<<<2048, 256, 0, stream>>>(x, Wq, Wk, Wv, Wo,
                                         xb, wqt, wkt, wvt, wot);

    dim3 gQKV(INNER / GN, M / GM, 3);
    qkv64<<<gQKV, 256, 0, stream>>>(xb, wqt, wkt, wvt, q, k, vt);

    dim3 gATT(64, BB * HH);
    attn_mfma<<<gATT, 256, 0, stream>>>(q, k, vt, lw, opart, lpart);

    dim3 gPRJ(DD / GN, M / GM);
    proj64<<<gPRJ, 256, 0, stream>>>(opart, lpart, wot, bo, out);
}